// Round 5
// baseline (176.624 us; speedup 1.0000x reference)
//
#include <hip/hip_runtime.h>

// Depthwise causal conv1d, k=3.
// x: (8, 768, 4096) fp32, weight: (768, 1, 3) fp32, y: (8, 768, 4096) fp32.
// y[n,c,t] = w[c,0]*x[t-2] + w[c,1]*x[t-1] + w[c,2]*x[t], zeros left of t=0.
//
// v6 = v5 with PLAIN stores (the only change). History of the A/B ladder:
//   v1  1 f4/thread, plain loads, nt stores           conv ~54 us
//   v3  4 contiguous f4/thread (64B stride) nt ld/st  conv  78 us  (coalescing broken)
//   v4  same layout, plain loads, nt stores           conv  97 us
//   v5  4 lane-contiguous segments, plain ld, nt st   conv ~56 us  (coalescing fixed)
// Traffic is already minimal (~207 MB vs 201 ideal) -> the 56-vs-33 us gap is
// effective BW. The float4-copy ceiling (6.3 TB/s) uses plain stores; our nt
// stores force y's 100 MB to HBM evict-first INSIDE the conv window (round-2
// counters: WRITE_SIZE 148-165 MB >> 100.7 MB output). Plain stores let the
// 256 MB memory-side Infinity Cache absorb y and defer writeback.
//
// Structure (unchanged from v5): one block per row; thread t owns float4
// indices {t, t+256, t+512, t+768}; every load/store instruction is
// lane-contiguous (1 KB per wave-instruction, fully-used 128 B lines).
// History per segment via __shfl_up from the previous lane; wave-lead lanes
// reload a float2 from global; t==0 zeros the causal edge.

#define CONV_L 4096
#define CONV_C 768

__global__ __launch_bounds__(256) void dwconv1d_k3_seg(
    const float* __restrict__ x,
    const float* __restrict__ w,
    float* __restrict__ y)
{
    const int row = blockIdx.x;          // 0..6143, block-uniform
    const int c   = row % CONV_C;        // uniform -> weight loads are scalar

    const float w0 = w[c * 3 + 0];
    const float w1 = w[c * 3 + 1];
    const float w2 = w[c * 3 + 2];

    const float* xrow = x + (size_t)row * CONV_L;
    float*       yrow = y + (size_t)row * CONV_L;

    const int t = threadIdx.x;           // float4 indices t + 256*j, j=0..3

    // 4 independent, each lane-contiguous (1 KB/wave-instruction) loads.
    const float4* xin = (const float4*)xrow;
    const float4 c0 = xin[t      ];
    const float4 c1 = xin[t + 256];
    const float4 c2 = xin[t + 512];
    const float4 c3 = xin[t + 768];

    // Per-segment history from the previous lane's float4 of the SAME segment.
    float m1_0 = __shfl_up(c0.w, 1), m2_0 = __shfl_up(c0.z, 1);
    float m1_1 = __shfl_up(c1.w, 1), m2_1 = __shfl_up(c1.z, 1);
    float m1_2 = __shfl_up(c2.w, 1), m2_2 = __shfl_up(c2.z, 1);
    float m1_3 = __shfl_up(c3.w, 1), m2_3 = __shfl_up(c3.z, 1);

    if ((t & 63) == 0) {
        // Segment j starts at float 4*(t+256j); history = floats 4p-2, 4p-1.
        if (t == 0) {
            m1_0 = 0.0f; m2_0 = 0.0f;    // causal left edge of the row
        } else {
            const float2 h = *(const float2*)(xrow + (t << 2) - 2);
            m2_0 = h.x; m1_0 = h.y;
        }
        const float2 h1 = *(const float2*)(xrow + ((t + 256) << 2) - 2);
        m2_1 = h1.x; m1_1 = h1.y;
        const float2 h2 = *(const float2*)(xrow + ((t + 512) << 2) - 2);
        m2_2 = h2.x; m1_2 = h2.y;
        const float2 h3 = *(const float2*)(xrow + ((t + 768) << 2) - 2);
        m2_3 = h3.x; m1_3 = h3.y;
    }

    float4* yout = (float4*)yrow;
    float4 o;

#define CONV_SEG(cc, m1, m2, off)                      \
    o.x = w0 * (m2)   + w1 * (m1)   + w2 * (cc).x;     \
    o.y = w0 * (m1)   + w1 * (cc).x + w2 * (cc).y;     \
    o.z = w0 * (cc).x + w1 * (cc).y + w2 * (cc).z;     \
    o.w = w0 * (cc).y + w1 * (cc).z + w2 * (cc).w;     \
    yout[t + (off)] = o;

    CONV_SEG(c0, m1_0, m2_0, 0)
    CONV_SEG(c1, m1_1, m2_1, 256)
    CONV_SEG(c2, m1_2, m2_2, 512)
    CONV_SEG(c3, m1_3, m2_3, 768)
#undef CONV_SEG
}

extern "C" void kernel_launch(void* const* d_in, const int* in_sizes, int n_in,
                              void* d_out, int out_size, void* d_ws, size_t ws_size,
                              hipStream_t stream)
{
    const float* x = (const float*)d_in[0];
    const float* w = (const float*)d_in[1];
    float* y = (float*)d_out;

    const int rows = out_size / CONV_L;   // out_size is ELEMENTS: 8*768 = 6144
    dwconv1d_k3_seg<<<rows, 256, 0, stream>>>(x, w, y);
}